// Round 13
// baseline (139.170 us; speedup 1.0000x reference)
//
#include <hip/hip_runtime.h>
#include <math.h>

#define NSITES 100000
#define NYEARS 20
#define HDIM 64
#define WSTR 72    // LDS weight row stride (f16 elems); 144B, 16B-aligned
#define NTILES 1563
#define NBLK 1024  // 4 blocks/CU x 256 CU: whole grid co-resident, zero rounds

typedef _Float16 f16x8 __attribute__((ext_vector_type(8)));
typedef _Float16 hx2   __attribute__((ext_vector_type(2)));
typedef float f32x4 __attribute__((ext_vector_type(4)));

__device__ __forceinline__ float sigmoidf_(float x) { return 1.0f / (1.0f + __expf(-x)); }
// fast elu: __expf(x)-1 (error ~1e-7, far below tolerance; result is f16-truncated anyway)
__device__ __forceinline__ float eluf_(float x) { return x > 0.0f ? x : __expf(x) - 1.0f; }

__device__ __forceinline__ unsigned pack2h_(float a, float b) {
    union { _Float16 h; unsigned short u; } x, y;
    x.h = (_Float16)a; y.h = (_Float16)b;
    return ((unsigned)y.u << 16) | (unsigned)x.u;
}

// load 8 consecutive f32 (32B-aligned) -> f16x8
__device__ __forceinline__ f16x8 cvt8h_(const float* p) {
    float4 a = ((const float4*)p)[0];
    float4 b = ((const float4*)p)[1];
    f16x8 r;
    r[0] = (_Float16)a.x; r[1] = (_Float16)a.y; r[2] = (_Float16)a.z; r[3] = (_Float16)a.w;
    r[4] = (_Float16)b.x; r[5] = (_Float16)b.y; r[6] = (_Float16)b.z; r[7] = (_Float16)b.w;
    return r;
}

// read 8 f16 (16B) from LDS weight tile at (row, col off)
__device__ __forceinline__ f16x8 ldsfrag_(const unsigned short* b, int row, int off) {
    union { f16x8 v; uint4 u; } r;
    r.u = *(const uint4*)&b[row * WSTR + off];
    return r.v;
}

union FragU { hx2 h2[4]; f16x8 v; };

// R25: PERSISTENT BLOCKS. R12-R24 falsification matrix is complete: occupancy,
// ILP, VALU volume, LDS footprint, staging style, MFMA chain depth -- none
// moves dur off ~44us; issue-work floor is ~7us, so 84% of issue slots idle
// with correlated stalls. The one untouched structural feature: the
// round/launch structure (1563 blocks = ~1.5 occupancy rounds, each block
// paying stage+h0-init+drain, CU partially draining between rounds).
// This round: grid = 1024 blocks (4/CU, whole grid co-resident), each block
// grid-strides over the 1563 site-tiles:
//  - weights staged ONCE per block (1563 -> 1024 stagings); a_hh / a_head /
//    biasD / wih2 register state loaded ONCE; successive tiles run
//    back-to-back in live waves -- no re-launch, no re-stage, no drain.
//  - logit overlay DROPPED (weights stay live): LDS = whh 9216 + wh1 9216 +
//    logits 10240 = 28672B. 2 barriers/tile sequence logit-write ->
//    epilogue-read -> next tile's writes.
//  - tile loop: tile = blockIdx.x; tile < 1563; tile += 1024 (539 blocks do
//    2 tiles, 485 do 1).
// Loop body = R24 (independent kt0/kt1 accumulators, f16 MFMA, packed-f16
// relu; validated R8/R10 permuted-output-row recurrence). launch_bounds(256,2)
// (the only binding that never spilled). Slot semantics: pL[sl*20+k] =
// p-logit(h_k) k=0..19; psiL[sl*20+k] = psi-logit(h_k) k=1..19, slot0=psi0.
__global__ __launch_bounds__(256, 2)
void rnet_kernel(const float* __restrict__ sxy0,
                 const float* __restrict__ sxy,
                 const float* __restrict__ oxy,
                 const float* __restrict__ W_h0, const float* __restrict__ b_h0,
                 const float* __restrict__ W_h1, const float* __restrict__ b_h1,
                 const float* __restrict__ W_ih, const float* __restrict__ b_ih,
                 const float* __restrict__ W_hh, const float* __restrict__ b_hh,
                 const float* __restrict__ W_psi0, const float* __restrict__ b_psi0,
                 const float* __restrict__ W_psi, const float* __restrict__ b_psi,
                 const float* __restrict__ W_p, const float* __restrict__ b_p,
                 float* __restrict__ out)
{
    const int tid  = threadIdx.x;       // 0..255
    const int lane = tid & 63;
    const int wv   = tid >> 6;          // wave 0..3
    const int s = lane & 15;            // site within wave / A-row within tile
    const int q = lane >> 4;            // quad
    const int sq = s >> 2, sr = s & 3;
    const int sl = wv * 16 + s;         // site local 0..63

    // ==== LDS: persistent weights + per-tile logit buffers (28672 B) ====
    __shared__ __align__(16) unsigned short whh_l[64 * WSTR];  // 9216 B
    __shared__ __align__(16) unsigned short wh1_l[64 * WSTR];  // 9216 B
    __shared__ __align__(16) float pL[64 * 20];                // 5120 B
    __shared__ __align__(16) float psiL[64 * 20];              // 5120 B

    float* __restrict__ out_psi0 = out;                 // [N]
    float* __restrict__ out_psi  = out + NSITES;        // [N,19]
    float* __restrict__ out_p    = out + 20 * NSITES;   // [N,20,2]

    // ==== stage weights ONCE per block (coalesced f32->f16) ====
    {
        const float4* whg = (const float4*)W_hh;
        const float4* w1g = (const float4*)W_h1;
#pragma unroll
        for (int j = 0; j < 4; ++j) {
            int e4 = j * 256 + tid;            // 0..1023 (1024 float4 = 64x64)
            int row = e4 >> 4, c4 = e4 & 15;
            float4 a = whg[e4];
            uint2 pa; pa.x = pack2h_(a.x, a.y); pa.y = pack2h_(a.z, a.w);
            *(uint2*)&whh_l[row * WSTR + c4 * 4] = pa;
            float4 b = w1g[e4];
            uint2 pb; pb.x = pack2h_(b.x, b.y); pb.y = pack2h_(b.z, b.w);
            *(uint2*)&wh1_l[row * WSTR + c4 * 4] = pb;
        }
    }
    __syncthreads();

    // ==== block-lifetime register state (loaded ONCE) ====
    f16x8 a_hh[4][2];
#pragma unroll
    for (int mt = 0; mt < 4; ++mt) {
        const int ar = 32 * (mt >> 1) + 8 * sq + 4 * (mt & 1) + sr;
#pragma unroll
        for (int kt = 0; kt < 2; ++kt)
            a_hh[mt][kt] = ldsfrag_(whh_l, ar, kt * 32 + q * 8);
    }
    f16x8 a_head[2];
    {
        const float* hrow = (s == 1) ? W_p : ((s == 2) ? W_psi0 : W_psi);
#pragma unroll
        for (int kt = 0; kt < 2; ++kt) a_head[kt] = cvt8h_(hrow + kt * 32 + q * 8);
    }
    f32x4 biasD[4];
    hx2 wih2[4][2];
#pragma unroll
    for (int mt = 0; mt < 4; ++mt) {
        const int dr = 32 * (mt >> 1) + 8 * q + 4 * (mt & 1);
        float4 bi = *(const float4*)(b_ih + dr);
        float4 bh = *(const float4*)(b_hh + dr);
        float4 wi = *(const float4*)(W_ih + dr);
        biasD[mt][0] = bi.x + bh.x; biasD[mt][1] = bi.y + bh.y;
        biasD[mt][2] = bi.z + bh.z; biasD[mt][3] = bi.w + bh.w;
        wih2[mt][0][0] = (_Float16)wi.x; wih2[mt][0][1] = (_Float16)wi.y;
        wih2[mt][1][0] = (_Float16)wi.z; wih2[mt][1][1] = (_Float16)wi.w;
    }
    f32x4 headC;
    headC[0] = (q == 0) ? b_psi[0]  : 0.0f;
    headC[1] = (q == 0) ? b_p[0]    : 0.0f;
    headC[2] = (q == 0) ? b_psi0[0] : 0.0f;
    headC[3] = 0.0f;
    f32x4 zc; zc[0] = 0.0f; zc[1] = 0.0f; zc[2] = 0.0f; zc[3] = 0.0f;
    const hx2 z2 = (hx2)(_Float16)0.0f;
    const float wpo = W_p[HDIM];
    const int p4max = (NSITES * 40) / 4;

    // ==== persistent tile loop ====
    for (int tile = blockIdx.x; tile < NTILES; tile += NBLK) {
        const int base = tile * 64;
        const int site = base + sl;
        const int site_ld = site < NSITES ? site : NSITES - 1;

        // ---- h0 stage: hs = elu(s0*W_h0+b_h0); h0 via permuted W_h1 (LDS) ----
        f16x8 bf[2];
        {
            const float s0v = sxy0[site_ld];
            f16x8 bf0[2];
#pragma unroll
            for (int kt = 0; kt < 2; ++kt) {
                const float* wp = W_h0 + kt * 32 + q * 8;
                const float* bp = b_h0 + kt * 32 + q * 8;
                float4 w0 = ((const float4*)wp)[0], w1 = ((const float4*)wp)[1];
                float4 c0 = ((const float4*)bp)[0], c1 = ((const float4*)bp)[1];
                float v[8];
                v[0] = eluf_(fmaf(s0v, w0.x, c0.x)); v[1] = eluf_(fmaf(s0v, w0.y, c0.y));
                v[2] = eluf_(fmaf(s0v, w0.z, c0.z)); v[3] = eluf_(fmaf(s0v, w0.w, c0.w));
                v[4] = eluf_(fmaf(s0v, w1.x, c1.x)); v[5] = eluf_(fmaf(s0v, w1.y, c1.y));
                v[6] = eluf_(fmaf(s0v, w1.z, c1.z)); v[7] = eluf_(fmaf(s0v, w1.w, c1.w));
#pragma unroll
                for (int j = 0; j < 8; ++j) bf0[kt][j] = (_Float16)v[j];
            }

            f32x4 acc[4];
#pragma unroll
            for (int mt = 0; mt < 4; ++mt) {
                const int dr = 32 * (mt >> 1) + 8 * q + 4 * (mt & 1);
                float4 b1 = *(const float4*)(b_h1 + dr);
                acc[mt][0] = b1.x; acc[mt][1] = b1.y; acc[mt][2] = b1.z; acc[mt][3] = b1.w;
            }
#pragma unroll
            for (int kt = 0; kt < 2; ++kt)
#pragma unroll
                for (int mt = 0; mt < 4; ++mt) {
                    const int ar = 32 * (mt >> 1) + 8 * sq + 4 * (mt & 1) + sr;
                    f16x8 a = ldsfrag_(wh1_l, ar, kt * 32 + q * 8);
                    acc[mt] = __builtin_amdgcn_mfma_f32_16x16x32_f16(a, bf0[kt], acc[mt], 0, 0, 0);
                }
            FragU f0, f1;
#pragma unroll
            for (int mt = 0; mt < 4; ++mt) {
                hx2 plo; plo[0] = (_Float16)eluf_(acc[mt][0]); plo[1] = (_Float16)eluf_(acc[mt][1]);
                hx2 phi; phi[0] = (_Float16)eluf_(acc[mt][2]); phi[1] = (_Float16)eluf_(acc[mt][3]);
                if (mt < 2) { f0.h2[mt * 2] = plo; f0.h2[mt * 2 + 1] = phi; }
                else        { f1.h2[(mt - 2) * 2] = plo; f1.h2[(mt - 2) * 2 + 1] = phi; }
            }
            bf[0] = f0.v;
            bf[1] = f1.v;
        }

        // previous tile's epilogue has fully read pL/psiL before we overwrite
        __syncthreads();

        const float* __restrict__ xs_g = sxy + (size_t)site_ld * 19;

        // ---- recurrence: ROLLED; kt0/kt1 MFMAs independent, merged in VALU ----
        float x = xs_g[0];
#pragma unroll 1
        for (int t = 1; t < NYEARS; ++t) {
            float x_next = (t < NYEARS - 1) ? xs_g[t] : 0.0f;

            f32x4 acc0[4], acc1[4], accH0, accH1;
#pragma unroll
            for (int mt = 0; mt < 4; ++mt)
                acc0[mt] = __builtin_amdgcn_mfma_f32_16x16x32_f16(a_hh[mt][0], bf[0], biasD[mt], 0, 0, 0);
            accH0 = __builtin_amdgcn_mfma_f32_16x16x32_f16(a_head[0], bf[0], headC, 0, 0, 0);
#pragma unroll
            for (int mt = 0; mt < 4; ++mt)
                acc1[mt] = __builtin_amdgcn_mfma_f32_16x16x32_f16(a_hh[mt][1], bf[1], zc, 0, 0, 0);
            accH1 = __builtin_amdgcn_mfma_f32_16x16x32_f16(a_head[1], bf[1], zc, 0, 0, 0);

            _Float16 xh = (_Float16)x;
            hx2 x2; x2[0] = xh; x2[1] = xh;
            FragU f0, f1;
#pragma unroll
            for (int mt = 0; mt < 4; ++mt) {
                f32x4 asum = acc0[mt] + acc1[mt];
                hx2 plo; plo[0] = (_Float16)asum[0]; plo[1] = (_Float16)asum[1];
                hx2 phi; phi[0] = (_Float16)asum[2]; phi[1] = (_Float16)asum[3];
                plo = __builtin_elementwise_max(plo + x2 * wih2[mt][0], z2);
                phi = __builtin_elementwise_max(phi + x2 * wih2[mt][1], z2);
                if (mt < 2) { f0.h2[mt * 2] = plo; f0.h2[mt * 2 + 1] = phi; }
                else        { f1.h2[(mt - 2) * 2] = plo; f1.h2[(mt - 2) * 2 + 1] = phi; }
            }
            bf[0] = f0.v;
            bf[1] = f1.v;

            if (q == 0) {
                // accH from bf = h_{t-1}: slot (t-1) semantics (R12-validated).
                pL[sl * 20 + (t - 1)]   = accH0[1] + accH1[1];
                psiL[sl * 20 + (t - 1)] = accH0[0] + accH1[0];
                if (t == 1) psiL[sl * 20] = accH0[2] + accH1[2];
            }
            x = x_next;
        }

        // ---- final heads on h_19 ----
        {
            f32x4 accH = __builtin_amdgcn_mfma_f32_16x16x32_f16(a_head[0], bf[0], headC, 0, 0, 0);
            accH = __builtin_amdgcn_mfma_f32_16x16x32_f16(a_head[1], bf[1], accH, 0, 0, 0);
            if (q == 0) {
                pL[sl * 20 + 19]   = accH[1];
                psiL[sl * 20 + 19] = accH[0];
            }
        }

        __syncthreads();   // logits complete before epilogue reads

        // ---- epilogue: sigmoid + oxy, 256 threads over 64 sites, guarded ----
        if (tid < 64 && base + tid < NSITES) out_psi0[base + tid] = sigmoidf_(psiL[tid * 20]);
#pragma unroll
        for (int r = 0; r < 5; ++r) {
            int i = r * 256 + tid;
            if (i < 64 * 19 && (size_t)base * 19 + i < (size_t)NSITES * 19) {
                int s2 = i / 19, c = i - s2 * 19;
                out_psi[(size_t)base * 19 + i] = sigmoidf_(psiL[s2 * 20 + c + 1]);
            }
        }
        const float4* oxy_b = (const float4*)(oxy + (size_t)base * 40);
        float4* outp_b = (float4*)(out_p + (size_t)base * 40);
#pragma unroll
        for (int r = 0; r < 3; ++r) {
            int i4 = r * 256 + tid;
            if (i4 < 640 && tile * 640 + i4 < p4max) {
                float4 ox = oxy_b[i4];
                float lg0 = pL[i4 * 2];
                float lg1 = pL[i4 * 2 + 1];
                float4 pv;
                pv.x = sigmoidf_(fmaf(wpo, ox.x, lg0));
                pv.y = sigmoidf_(fmaf(wpo, ox.y, lg0));
                pv.z = sigmoidf_(fmaf(wpo, ox.z, lg1));
                pv.w = sigmoidf_(fmaf(wpo, ox.w, lg1));
                outp_b[i4] = pv;
            }
        }
    }
}

extern "C" void kernel_launch(void* const* d_in, const int* in_sizes, int n_in,
                              void* d_out, int out_size, void* d_ws, size_t ws_size,
                              hipStream_t stream) {
    const float* sxy0   = (const float*)d_in[0];
    const float* sxy    = (const float*)d_in[1];
    const float* oxy    = (const float*)d_in[2];
    const float* W_h0   = (const float*)d_in[3];
    const float* b_h0   = (const float*)d_in[4];
    const float* W_h1   = (const float*)d_in[5];
    const float* b_h1   = (const float*)d_in[6];
    const float* W_ih   = (const float*)d_in[7];
    const float* b_ih   = (const float*)d_in[8];
    const float* W_hh   = (const float*)d_in[9];
    const float* b_hh   = (const float*)d_in[10];
    const float* W_psi0 = (const float*)d_in[11];
    const float* b_psi0 = (const float*)d_in[12];
    const float* W_psi  = (const float*)d_in[13];
    const float* b_psi  = (const float*)d_in[14];
    const float* W_p    = (const float*)d_in[15];
    const float* b_p    = (const float*)d_in[16];

    float* out = (float*)d_out;

    dim3 block(256);
    dim3 grid(NBLK);   // 1024 persistent blocks (4/CU), grid-stride over 1563 tiles
    rnet_kernel<<<grid, block, 0, stream>>>(
        sxy0, sxy, oxy, W_h0, b_h0, W_h1, b_h1, W_ih, b_ih, W_hh, b_hh,
        W_psi0, b_psi0, W_psi, b_psi, W_p, b_p, out);
}